// Round 6
// baseline (810.221 us; speedup 1.0000x reference)
//
#include <hip/hip_runtime.h>

#define T_STEPS 500
#define BATCH   128
#define NINPUT  6
#define NH      500
#define THRV    1.0f
#define BETAV   0.5f
#define W2T_STRIDE 512
#define NGC     8      // j-chunks of 64 outputs

typedef unsigned long long ull;

static __device__ __forceinline__ ull rfl64(ull v) {
  unsigned lo = __builtin_amdgcn_readfirstlane((unsigned)v);
  unsigned hi = __builtin_amdgcn_readfirstlane((unsigned)(v >> 32));
  return ((ull)hi << 32) | lo;
}

// ---------------------------------------------------------------------------
// Transpose W2 [500][500] -> W2T [500][512] (padded stride, pad zeroed).
// ---------------------------------------------------------------------------
__global__ void transpose_w2(const float* __restrict__ W2, float* __restrict__ W2T) {
  int idx = blockIdx.x * 256 + threadIdx.x;
  if (idx < NH * W2T_STRIDE) {
    int i = idx >> 9;
    int j = idx & 511;
    W2T[idx] = (j < NH) ? W2[j * NH + i] : 0.f;
  }
}

// ---------------------------------------------------------------------------
// s1_seg: layer-1 LIF for t in [t0, t0+tc). grid = 128 (b), 512 thr = 8 waves.
// Wave w owns neurons [64w, 64w+64); ballot -> one mask word per step.
// m1 carried in m1state across segments (init at t0==0).
// ---------------------------------------------------------------------------
__global__ __launch_bounds__(512) void s1_seg_kernel(
    const float* __restrict__ x,      // [T][B][6]
    const float* __restrict__ W1,     // [500][6]
    const float* __restrict__ b1,     // [500]
    float* __restrict__ m1state,      // [B][512]
    ull* __restrict__ s1seg,          // [tc][B][8]
    int t0, int tc)
{
  const int b = blockIdx.x;
  const int wid = threadIdx.x >> 6, lane = threadIdx.x & 63;
  const int n = (wid << 6) + lane;
  const bool nv = (n < NH);

  float w[6], b1v;
  #pragma unroll
  for (int k = 0; k < 6; ++k) w[k] = nv ? W1[n * NINPUT + k] : 0.f;
  b1v = nv ? b1[n] : 0.f;
  float m1 = (t0 == 0) ? 0.f : m1state[b * 512 + n];

  float xa[6], xb[6];
  {
    const float* xp = x + (size_t)(t0 * BATCH + b) * NINPUT;
    float2 a = *(const float2*)xp, c = *(const float2*)(xp + 2), d = *(const float2*)(xp + 4);
    xa[0]=a.x; xa[1]=a.y; xa[2]=c.x; xa[3]=c.y; xa[4]=d.x; xa[5]=d.y;
  }
  for (int h = 0; h < tc; ++h) {
    int tn = t0 + h + 1; if (tn > T_STEPS - 1) tn = T_STEPS - 1;
    const float* xp = x + (size_t)(tn * BATCH + b) * NINPUT;
    float2 a = *(const float2*)xp, c = *(const float2*)(xp + 2), d = *(const float2*)(xp + 4);
    xb[0]=a.x; xb[1]=a.y; xb[2]=c.x; xb[3]=c.y; xb[4]=d.x; xb[5]=d.y;

    float cur = b1v + w[0]*xa[0] + w[1]*xa[1] + w[2]*xa[2]
                    + w[3]*xa[3] + w[4]*xa[4] + w[5]*xa[5];
    float rst = (m1 > THRV) ? THRV : 0.f;
    m1 = BETAV * m1 + cur - rst;
    ull bm = __ballot((m1 > THRV) && nv);
    if (lane == 0) s1seg[((size_t)h * BATCH + b) * 8 + wid] = bm;

    #pragma unroll
    for (int k = 0; k < 6; ++k) xa[k] = xb[k];
  }
  m1state[b * 512 + n] = m1;
}

// ---------------------------------------------------------------------------
// cur2_seg: cur2[h][b][j] = b2[j] + sum_{i active} W2[j][i].
// Fully parallel over (h, b). grid = (128 b, 8 jc), 512 thr = 8 waves.
// W2 chunk [500][64] staged in LDS (128 KB). Wave handles h = wid, wid+8, ...
// Masks are wave-uniform -> readfirstlane -> SALU peel; per active row:
// 1 addr add + 1 ds_read_b32 + 1 fadd (2-deep peel for LDS latency ILP).
// ---------------------------------------------------------------------------
__global__ __launch_bounds__(512) void cur2_seg_kernel(
    const ull* __restrict__ s1seg,    // [tc][B][8]
    const float* __restrict__ W2T,    // [500][512]
    const float* __restrict__ b2,     // [500]
    float* __restrict__ cur2seg,      // [tc][B][500]
    int tc)
{
  __shared__ float W2L[NH * 64];
  const int b = blockIdx.x, jc = blockIdx.y;
  const int tid = threadIdx.x;
  const int lane = tid & 63, wid = tid >> 6;

  for (int idx = tid; idx < NH * 64; idx += 512) {
    int i = idx >> 6, jl = idx & 63;
    W2L[idx] = W2T[i * W2T_STRIDE + jc * 64 + jl];
  }
  const int j = jc * 64 + lane;
  const float b2v = (j < NH) ? b2[j] : 0.f;
  __syncthreads();

  for (int h = wid; h < tc; h += 8) {
    const ull* p = s1seg + ((size_t)h * BATCH + b) * 8;
    ull q[8];
    #pragma unroll
    for (int k = 0; k < 8; ++k) q[k] = p[k];

    float acc = 0.f, acc2 = 0.f;
    #pragma unroll
    for (int k = 0; k < 8; ++k) {
      ull m = rfl64(q[k]);
      const float* base = W2L + (k << 12) + lane;   // (k*64)*64 + lane
      while (m) {
        int i0 = __builtin_ctzll(m); m &= m - 1;
        float v0 = base[i0 << 6];
        if (m) {
          int i1 = __builtin_ctzll(m); m &= m - 1;
          acc2 += base[i1 << 6];
        }
        acc += v0;
      }
    }
    float cur = (acc + acc2) + b2v;
    if (j < NH) cur2seg[((size_t)h * BATCH + b) * NH + j] = cur;
  }
}

// ---------------------------------------------------------------------------
// scan2_seg: m2 recurrence, parallel over (b, j). grid = 128 (b), 512 thr.
// Thread j scans its chain over the segment; 4-deep static prefetch.
// s2 masks ballot-packed per wave (wave w <-> j in [64w, 64w+64)).
// ---------------------------------------------------------------------------
__global__ __launch_bounds__(512) void scan2_seg_kernel(
    const float* __restrict__ cur2seg, // [tc][B][500]
    float* __restrict__ m2state,       // [B][512]
    ull* __restrict__ s2seg,           // [tc][B][8]
    int t0, int tc)
{
  const int b = blockIdx.x;
  const int tid = threadIdx.x;
  const int lane = tid & 63, wid = tid >> 6;
  const int j = tid;
  const bool jv = (j < NH);

  float m2 = (t0 == 0) ? 0.f : m2state[b * 512 + j];

  #define LD2(h) ((jv && (h) < tc) ? cur2seg[((size_t)((h) < tc ? (h) : 0) * BATCH + b) * NH + j] : 0.f)
  float v0 = LD2(0), v1 = LD2(1), v2 = LD2(2), v3 = LD2(3);

  for (int h = 0; h < tc; h += 4) {
    #define PROC(hh, vv) do {                                         \
      if ((hh) < tc) {                                                \
        float rst_ = (m2 > THRV) ? THRV : 0.f;                        \
        m2 = BETAV * m2 + (vv) - rst_;                                \
        ull bm_ = __ballot((m2 > THRV) && jv);                        \
        if (lane == 0) s2seg[((size_t)(hh) * BATCH + b) * 8 + wid] = bm_; \
      }                                                               \
    } while (0)
    PROC(h, v0);     v0 = LD2(h + 4);
    PROC(h + 1, v1); v1 = LD2(h + 5);
    PROC(h + 2, v2); v2 = LD2(h + 6);
    PROC(h + 3, v3); v3 = LD2(h + 7);
    #undef PROC
  }
  #undef LD2
  m2state[b * 512 + j] = m2;
}

// ---------------------------------------------------------------------------
// cur3_seg: cur3[t][b][2] = Wout . s2 -- parallel over seg pairs.
// ---------------------------------------------------------------------------
__global__ __launch_bounds__(256) void cur3_seg_kernel(
    const ull* __restrict__ s2seg,    // [tc][B][8]
    const float* __restrict__ Wout,   // [2][500]
    float* __restrict__ cur3,         // [T*B][2]
    int t0, int tc)
{
  const int wid  = threadIdx.x >> 6;
  const int lane = threadIdx.x & 63;
  const int pl = blockIdx.x * 4 + wid;
  if (pl >= tc * BATCH) return;

  float wa[NGC], wb[NGC];
  #pragma unroll
  for (int g = 0; g < NGC; ++g) {
    int j = g * 64 + lane;
    wa[g] = (j < NH) ? Wout[j] : 0.f;
    wb[g] = (j < NH) ? Wout[NH + j] : 0.f;
  }

  const ull* p = s2seg + (size_t)pl * 8;
  float c0 = 0.f, c1 = 0.f;
  #pragma unroll
  for (int g = 0; g < NGC; ++g) {
    ull mg = p[g];
    if ((mg >> lane) & 1ull) { c0 += wa[g]; c1 += wb[g]; }
  }
  #pragma unroll
  for (int off = 32; off; off >>= 1) {
    c0 += __shfl_xor(c0, off);
    c1 += __shfl_xor(c1, off);
  }
  if (lane == 0)
    *(float2*)(cur3 + ((size_t)t0 * BATCH + pl) * 2) = make_float2(c0, c1);
}

// ---------------------------------------------------------------------------
// scan3: serial m3 scan, one thread per batch element, 8-deep prefetch.
// ---------------------------------------------------------------------------
__global__ __launch_bounds__(128) void scan3_kernel(
    const float* __restrict__ cur3,  // [T*B][2]
    const float* __restrict__ bout,  // [2]
    float* __restrict__ out)         // spk [T][B][2] then mem [T][B][2]
{
  const int b = threadIdx.x;
  const float bo0 = bout[0], bo1 = bout[1];
  float m0 = 0.f, m1v = 0.f;

  float2 cbuf[8], nbuf[8];
  #pragma unroll
  for (int k = 0; k < 8; ++k)
    cbuf[k] = *(const float2*)(cur3 + (size_t)(k * BATCH + b) * 2);

  for (int tc = 0; tc < T_STEPS; tc += 8) {
    #pragma unroll
    for (int k = 0; k < 8; ++k) {
      int tn = tc + 8 + k; if (tn > T_STEPS - 1) tn = T_STEPS - 1;
      nbuf[k] = *(const float2*)(cur3 + (size_t)(tn * BATCH + b) * 2);
    }
    #pragma unroll
    for (int k = 0; k < 8; ++k) {
      int t = tc + k;
      if (t < T_STEPS) {
        float c0 = cbuf[k].x + bo0, c1 = cbuf[k].y + bo1;
        float r0 = (m0  > THRV) ? THRV : 0.f;
        float r1 = (m1v > THRV) ? THRV : 0.f;
        m0  = BETAV * m0  + c0 - r0;
        m1v = BETAV * m1v + c1 - r1;
        size_t o = (size_t)(t * BATCH + b) * 2;
        out[o]     = (m0  > THRV) ? 1.f : 0.f;
        out[o + 1] = (m1v > THRV) ? 1.f : 0.f;
        out[(size_t)T_STEPS * BATCH * 2 + o]     = m0;
        out[(size_t)T_STEPS * BATCH * 2 + o + 1] = m1v;
      }
    }
    #pragma unroll
    for (int k = 0; k < 8; ++k) cbuf[k] = nbuf[k];
  }
}

extern "C" void kernel_launch(void* const* d_in, const int* in_sizes, int n_in,
                              void* d_out, int out_size, void* d_ws, size_t ws_size,
                              hipStream_t stream) {
  const float* x    = (const float*)d_in[0];
  const float* W1   = (const float*)d_in[1];
  const float* b1   = (const float*)d_in[2];
  const float* W2   = (const float*)d_in[3];
  const float* b2   = (const float*)d_in[4];
  const float* Wout = (const float*)d_in[5];
  const float* bout = (const float*)d_in[6];
  float* out = (float*)d_out;

  // ---- carve workspace (all 512-aligned) ----
  size_t off = 0;
  char* base = (char*)d_ws;
  auto carve = [&](size_t bytes) -> char* {
    char* r = base + off;
    off += (bytes + 511) & ~(size_t)511;
    return r;
  };
  float* W2T     = (float*)carve((size_t)NH * W2T_STRIDE * 4);   // 1,024,000
  float* m1state = (float*)carve((size_t)BATCH * 512 * 4);       //   262,144
  float* m2state = (float*)carve((size_t)BATCH * 512 * 4);       //   262,144
  float* cur3    = (float*)carve((size_t)T_STEPS * BATCH * 2 * 4); // 512,000

  // segment size from remaining workspace
  const size_t per_t = ((size_t)BATCH * 8 * 8)      // s1seg
                     + ((size_t)BATCH * 8 * 8)      // s2seg
                     + ((size_t)BATCH * NH * 4);    // cur2seg  = 272,384
  long long avail = (long long)ws_size - (long long)off - 4096;
  int TSEG = (avail > 0) ? (int)(avail / (long long)per_t) : 1;
  if (TSEG > T_STEPS) TSEG = T_STEPS;
  if (TSEG < 1) TSEG = 1;

  ull*   s1seg   = (ull*)carve((size_t)TSEG * BATCH * 8 * 8);
  ull*   s2seg   = (ull*)carve((size_t)TSEG * BATCH * 8 * 8);
  float* cur2seg = (float*)carve((size_t)TSEG * BATCH * NH * 4);

  transpose_w2<<<(NH * W2T_STRIDE + 255) / 256, 256, 0, stream>>>(W2, W2T);

  for (int t0 = 0; t0 < T_STEPS; t0 += TSEG) {
    int tc = T_STEPS - t0; if (tc > TSEG) tc = TSEG;
    s1_seg_kernel<<<BATCH, 512, 0, stream>>>(x, W1, b1, m1state, s1seg, t0, tc);
    cur2_seg_kernel<<<dim3(BATCH, NGC), 512, 0, stream>>>(s1seg, W2T, b2, cur2seg, tc);
    scan2_seg_kernel<<<BATCH, 512, 0, stream>>>(cur2seg, m2state, s2seg, t0, tc);
    cur3_seg_kernel<<<(tc * BATCH + 3) / 4, 256, 0, stream>>>(s2seg, Wout, cur3, t0, tc);
  }
  scan3_kernel<<<1, 128, 0, stream>>>(cur3, bout, out);
}

// Round 8
// 451.835 us; speedup vs baseline: 1.7932x; 1.7932x over previous
//
#include <hip/hip_runtime.h>

#define T_STEPS 500
#define BATCH   128
#define NINPUT  6
#define NH      500
#define THRV    1.0f
#define BETAV   0.5f
#define W2T_STRIDE 512
#define NGC     8      // s2 mask words per (t,b)
#define JC      256    // j-chunk width in cur2
#define KT      128    // W2 rows per LDS tile

typedef unsigned long long ull;

static __device__ __forceinline__ ull rfl64(ull v) {
  unsigned lo = __builtin_amdgcn_readfirstlane((unsigned)v);
  unsigned hi = __builtin_amdgcn_readfirstlane((unsigned)(v >> 32));
  return ((ull)hi << 32) | lo;
}

// ---------------------------------------------------------------------------
// Transpose W2 [500][500] -> W2T [500][512] (padded stride, pad zeroed).
// ---------------------------------------------------------------------------
__global__ void transpose_w2(const float* __restrict__ W2, float* __restrict__ W2T) {
  int idx = blockIdx.x * 256 + threadIdx.x;
  if (idx < NH * W2T_STRIDE) {
    int i = idx >> 9;
    int j = idx & 511;
    W2T[idx] = (j < NH) ? W2[j * NH + i] : 0.f;
  }
}

// ---------------------------------------------------------------------------
// s1_seg: layer-1 LIF for t in [t0, t0+tc). grid = 128 (b), 512 thr = 8 waves.
// x slice for this b staged into LDS once (12 KB); 2-deep LDS prefetch.
// Wave w owns neurons [64w, 64w+64); ballot -> one mask word per step.
// ---------------------------------------------------------------------------
__global__ __launch_bounds__(512) void s1_seg_kernel(
    const float* __restrict__ x,      // [T][B][6]
    const float* __restrict__ W1,     // [500][6]
    const float* __restrict__ b1,     // [500]
    float* __restrict__ m1state,      // [B][512]
    ull* __restrict__ s1seg,          // [tc][B][8]
    int t0, int tc)
{
  __shared__ float xs[T_STEPS * NINPUT];   // 12 KB max
  const int b = blockIdx.x;
  const int wid = threadIdx.x >> 6, lane = threadIdx.x & 63;

  for (int idx = threadIdx.x; idx < tc * NINPUT; idx += 512) {
    int h = idx / NINPUT, k = idx - h * NINPUT;
    xs[idx] = x[(size_t)((t0 + h) * BATCH + b) * NINPUT + k];
  }

  const int n = (wid << 6) + lane;
  const bool nv = (n < NH);
  float w[6], b1v;
  #pragma unroll
  for (int k = 0; k < 6; ++k) w[k] = nv ? W1[n * NINPUT + k] : 0.f;
  b1v = nv ? b1[n] : 0.f;
  float m1 = (t0 == 0) ? 0.f : m1state[b * 512 + n];

  __syncthreads();

  #define LOADL(hh, xr) do {                                   \
    const float* p_ = xs + (hh) * NINPUT;                      \
    float2 a_ = *(const float2*)p_;                            \
    float2 c_ = *(const float2*)(p_ + 2);                      \
    float2 d_ = *(const float2*)(p_ + 4);                      \
    xr[0]=a_.x; xr[1]=a_.y; xr[2]=c_.x;                        \
    xr[3]=c_.y; xr[4]=d_.x; xr[5]=d_.y;                        \
  } while (0)

  float X0[6], X1[6], X2[6];
  LOADL(0, X0);
  if (tc > 1) LOADL(1, X1); else LOADL(0, X1);

  for (int h = 0; h < tc; ++h) {
    int hp = h + 2; if (hp > tc - 1) hp = tc - 1;
    LOADL(hp, X2);
    float cur = b1v + w[0]*X0[0] + w[1]*X0[1] + w[2]*X0[2]
                    + w[3]*X0[3] + w[4]*X0[4] + w[5]*X0[5];
    float rst = (m1 > THRV) ? THRV : 0.f;
    m1 = BETAV * m1 + cur - rst;
    ull bm = __ballot((m1 > THRV) && nv);
    if (lane == 0) s1seg[((size_t)h * BATCH + b) * 8 + wid] = bm;
    #pragma unroll
    for (int k = 0; k < 6; ++k) { X0[k] = X1[k]; X1[k] = X2[k]; }
  }
  #undef LOADL
  m1state[b * 512 + n] = m1;
}

// ---------------------------------------------------------------------------
// cur2_seg: cur2[h][b][j] = b2[j] + sum_{i active} W2[j][i].
// grid = (128 b, 2 jc), 512 thr = 8 waves, 1 block/CU (128 KB LDS).
// Lane owns 4 consecutive j -> ds_read_b128 per active row (4x fewer LDS
// instrs than b32). W2 K-tiled: 4 tiles of 128 rows x 256 j in LDS; masks
// (wave-uniform, SALU-peeled 2-wide) select rows. Wave owns h = r*128+g*8+wid,
// acc = float4[16] in regs across the 4 K-tiles of a round.
// ---------------------------------------------------------------------------
__global__ __launch_bounds__(512) void cur2_seg_kernel(
    const ull* __restrict__ s1seg,    // [tc][B][8]
    const float* __restrict__ W2T,    // [500][512]
    const float* __restrict__ b2,     // [500]
    float* __restrict__ cur2seg,      // [tc][B][500]
    int tc)
{
  __shared__ float4 W2L[KT * (JC / 4)];   // 128 x 64 float4 = 128 KB
  const int b = blockIdx.x, jc = blockIdx.y;
  const int tid = threadIdx.x;
  const int lane = tid & 63, wid = tid >> 6;
  const int j0 = jc * JC + (lane << 2);   // lane covers j0..j0+3
  const bool jv = (j0 < NH);

  float4 b2v = make_float4(0.f, 0.f, 0.f, 0.f);
  if (jv) b2v = *(const float4*)(b2 + j0);

  for (int r = 0; r < 4; ++r) {
    float4 acc[16];
    #pragma unroll
    for (int g = 0; g < 16; ++g) acc[g] = make_float4(0.f, 0.f, 0.f, 0.f);

    for (int kt = 0; kt < 4; ++kt) {
      __syncthreads();
      // stage tile kt: rows [kt*128, kt*128+128) x cols [jc*256, +256)
      for (int idx = tid; idx < KT * (JC / 4); idx += 512) {
        int rr = idx >> 6, cc = idx & 63;
        int grow = kt * KT + rr;
        float4 v = make_float4(0.f, 0.f, 0.f, 0.f);
        if (grow < NH)
          v = *(const float4*)(W2T + (size_t)grow * W2T_STRIDE + jc * JC + (cc << 2));
        W2L[idx] = v;
      }
      __syncthreads();

      #pragma unroll
      for (int g = 0; g < 16; ++g) {
        const int h = r * 128 + g * 8 + wid;
        if (h < tc) {
          const ull* mp = s1seg + ((size_t)h * BATCH + b) * 8 + 2 * kt;
          ull mA = rfl64(mp[0]);
          ull mB = rfl64(mp[1]);
          while (mA) {   // tile rows 0-63
            int i0 = __builtin_ctzll(mA); mA &= mA - 1;
            bool h2 = (mA != 0);
            int i1 = h2 ? __builtin_ctzll(mA) : i0;
            if (h2) mA &= mA - 1;
            float4 v0 = W2L[(i0 << 6) + lane];
            float4 v1 = W2L[(i1 << 6) + lane];
            acc[g].x += v0.x; acc[g].y += v0.y; acc[g].z += v0.z; acc[g].w += v0.w;
            if (h2) { acc[g].x += v1.x; acc[g].y += v1.y; acc[g].z += v1.z; acc[g].w += v1.w; }
          }
          while (mB) {   // tile rows 64-127
            int i0 = __builtin_ctzll(mB); mB &= mB - 1;
            bool h2 = (mB != 0);
            int i1 = h2 ? __builtin_ctzll(mB) : i0;
            if (h2) mB &= mB - 1;
            float4 v0 = W2L[((64 + i0) << 6) + lane];
            float4 v1 = W2L[((64 + i1) << 6) + lane];
            acc[g].x += v0.x; acc[g].y += v0.y; acc[g].z += v0.z; acc[g].w += v0.w;
            if (h2) { acc[g].x += v1.x; acc[g].y += v1.y; acc[g].z += v1.z; acc[g].w += v1.w; }
          }
        }
      }
    }

    // write round r's outputs (float4, 16B-aligned: 500*4 % 16 == 0, j0 % 4 == 0)
    #pragma unroll
    for (int g = 0; g < 16; ++g) {
      const int h = r * 128 + g * 8 + wid;
      if (h < tc && jv) {
        float4 v = make_float4(acc[g].x + b2v.x, acc[g].y + b2v.y,
                               acc[g].z + b2v.z, acc[g].w + b2v.w);
        *(float4*)(cur2seg + ((size_t)h * BATCH + b) * NH + j0) = v;
      }
    }
  }
}

// ---------------------------------------------------------------------------
// scan2_seg: m2 recurrence, parallel over (b, j). grid = (128 b, 2 jh),
// 256 thr. Thread j scans its chain; 8-deep static prefetch.
// Wave wid <-> s2 word jh*4+wid.
// ---------------------------------------------------------------------------
__global__ __launch_bounds__(256) void scan2_seg_kernel(
    const float* __restrict__ cur2seg, // [tc][B][500]
    float* __restrict__ m2state,       // [B][512]
    ull* __restrict__ s2seg,           // [tc][B][8]
    int t0, int tc)
{
  const int b = blockIdx.x, jh = blockIdx.y;
  const int tid = threadIdx.x;
  const int lane = tid & 63, wid = tid >> 6;
  const int j = jh * 256 + tid;
  const bool jv = (j < NH);
  const int word = jh * 4 + wid;

  float m2 = (t0 == 0) ? 0.f : m2state[b * 512 + j];

  #define LD2(h) ((jv && (h) < tc) ? cur2seg[((size_t)((h) < tc ? (h) : 0) * BATCH + b) * NH + j] : 0.f)
  float v[8], nv_[8];
  #pragma unroll
  for (int k = 0; k < 8; ++k) v[k] = LD2(k);

  for (int hc = 0; hc < tc; hc += 8) {
    #pragma unroll
    for (int k = 0; k < 8; ++k) nv_[k] = LD2(hc + 8 + k);
    #pragma unroll
    for (int k = 0; k < 8; ++k) {
      int h = hc + k;
      if (h < tc) {
        float rst = (m2 > THRV) ? THRV : 0.f;
        m2 = BETAV * m2 + v[k] - rst;
        ull bm = __ballot((m2 > THRV) && jv);
        if (lane == 0) s2seg[((size_t)h * BATCH + b) * 8 + word] = bm;
      }
    }
    #pragma unroll
    for (int k = 0; k < 8; ++k) v[k] = nv_[k];
  }
  #undef LD2
  m2state[b * 512 + j] = m2;
}

// ---------------------------------------------------------------------------
// cur3_seg: cur3[t][b][2] = Wout . s2 -- parallel over seg pairs.
// ---------------------------------------------------------------------------
__global__ __launch_bounds__(256) void cur3_seg_kernel(
    const ull* __restrict__ s2seg,    // [tc][B][8]
    const float* __restrict__ Wout,   // [2][500]
    float* __restrict__ cur3,         // [T*B][2]
    int t0, int tc)
{
  const int wid  = threadIdx.x >> 6;
  const int lane = threadIdx.x & 63;
  const int pl = blockIdx.x * 4 + wid;
  if (pl >= tc * BATCH) return;

  float wa[NGC], wb[NGC];
  #pragma unroll
  for (int g = 0; g < NGC; ++g) {
    int j = g * 64 + lane;
    wa[g] = (j < NH) ? Wout[j] : 0.f;
    wb[g] = (j < NH) ? Wout[NH + j] : 0.f;
  }

  const ull* p = s2seg + (size_t)pl * 8;
  float c0 = 0.f, c1 = 0.f;
  #pragma unroll
  for (int g = 0; g < NGC; ++g) {
    ull mg = p[g];
    if ((mg >> lane) & 1ull) { c0 += wa[g]; c1 += wb[g]; }
  }
  #pragma unroll
  for (int off = 32; off; off >>= 1) {
    c0 += __shfl_xor(c0, off);
    c1 += __shfl_xor(c1, off);
  }
  if (lane == 0)
    *(float2*)(cur3 + ((size_t)t0 * BATCH + pl) * 2) = make_float2(c0, c1);
}

// ---------------------------------------------------------------------------
// scan3: serial m3 scan, one thread per batch element, 8-deep prefetch.
// ---------------------------------------------------------------------------
__global__ __launch_bounds__(128) void scan3_kernel(
    const float* __restrict__ cur3,  // [T*B][2]
    const float* __restrict__ bout,  // [2]
    float* __restrict__ out)         // spk [T][B][2] then mem [T][B][2]
{
  const int b = threadIdx.x;
  const float bo0 = bout[0], bo1 = bout[1];
  float m0 = 0.f, m1v = 0.f;

  float2 cbuf[8], nbuf[8];
  #pragma unroll
  for (int k = 0; k < 8; ++k)
    cbuf[k] = *(const float2*)(cur3 + (size_t)(k * BATCH + b) * 2);

  for (int tcc = 0; tcc < T_STEPS; tcc += 8) {
    #pragma unroll
    for (int k = 0; k < 8; ++k) {
      int tn = tcc + 8 + k; if (tn > T_STEPS - 1) tn = T_STEPS - 1;
      nbuf[k] = *(const float2*)(cur3 + (size_t)(tn * BATCH + b) * 2);
    }
    #pragma unroll
    for (int k = 0; k < 8; ++k) {
      int t = tcc + k;
      if (t < T_STEPS) {
        float c0 = cbuf[k].x + bo0, c1 = cbuf[k].y + bo1;
        float r0 = (m0  > THRV) ? THRV : 0.f;
        float r1 = (m1v > THRV) ? THRV : 0.f;
        m0  = BETAV * m0  + c0 - r0;
        m1v = BETAV * m1v + c1 - r1;
        size_t o = (size_t)(t * BATCH + b) * 2;
        out[o]     = (m0  > THRV) ? 1.f : 0.f;
        out[o + 1] = (m1v > THRV) ? 1.f : 0.f;
        out[(size_t)T_STEPS * BATCH * 2 + o]     = m0;
        out[(size_t)T_STEPS * BATCH * 2 + o + 1] = m1v;
      }
    }
    #pragma unroll
    for (int k = 0; k < 8; ++k) cbuf[k] = nbuf[k];
  }
}

extern "C" void kernel_launch(void* const* d_in, const int* in_sizes, int n_in,
                              void* d_out, int out_size, void* d_ws, size_t ws_size,
                              hipStream_t stream) {
  const float* x    = (const float*)d_in[0];
  const float* W1   = (const float*)d_in[1];
  const float* b1   = (const float*)d_in[2];
  const float* W2   = (const float*)d_in[3];
  const float* b2   = (const float*)d_in[4];
  const float* Wout = (const float*)d_in[5];
  const float* bout = (const float*)d_in[6];
  float* out = (float*)d_out;

  // ---- carve workspace (all 512-aligned) ----
  size_t off = 0;
  char* base = (char*)d_ws;
  auto carve = [&](size_t bytes) -> char* {
    char* r = base + off;
    off += (bytes + 511) & ~(size_t)511;
    return r;
  };
  float* W2T     = (float*)carve((size_t)NH * W2T_STRIDE * 4);
  float* m1state = (float*)carve((size_t)BATCH * 512 * 4);
  float* m2state = (float*)carve((size_t)BATCH * 512 * 4);
  float* cur3    = (float*)carve((size_t)T_STEPS * BATCH * 2 * 4);

  const size_t per_t = ((size_t)BATCH * 8 * 8)      // s1seg
                     + ((size_t)BATCH * 8 * 8)      // s2seg
                     + ((size_t)BATCH * NH * 4);    // cur2seg
  long long avail = (long long)ws_size - (long long)off - 4096;
  int TSEG = (avail > 0) ? (int)(avail / (long long)per_t) : 1;
  if (TSEG > T_STEPS) TSEG = T_STEPS;
  if (TSEG < 1) TSEG = 1;

  ull*   s1seg   = (ull*)carve((size_t)TSEG * BATCH * 8 * 8);
  ull*   s2seg   = (ull*)carve((size_t)TSEG * BATCH * 8 * 8);
  float* cur2seg = (float*)carve((size_t)TSEG * BATCH * NH * 4);

  transpose_w2<<<(NH * W2T_STRIDE + 255) / 256, 256, 0, stream>>>(W2, W2T);

  for (int t0 = 0; t0 < T_STEPS; t0 += TSEG) {
    int tc = T_STEPS - t0; if (tc > TSEG) tc = TSEG;
    s1_seg_kernel<<<BATCH, 512, 0, stream>>>(x, W1, b1, m1state, s1seg, t0, tc);
    cur2_seg_kernel<<<dim3(BATCH, 2), 512, 0, stream>>>(s1seg, W2T, b2, cur2seg, tc);
    scan2_seg_kernel<<<dim3(BATCH, 2), 256, 0, stream>>>(cur2seg, m2state, s2seg, t0, tc);
    cur3_seg_kernel<<<(tc * BATCH + 3) / 4, 256, 0, stream>>>(s2seg, Wout, cur3, t0, tc);
  }
  scan3_kernel<<<1, 128, 0, stream>>>(cur3, bout, out);
}